// Round 5
// baseline (87.047 us; speedup 1.0000x reference)
//
#include <hip/hip_runtime.h>

#define EPSF 1e-8f
#define FPB 4      // frames per block-group
#define BLOCK 256
#define AT 4       // atoms register-cached per chunk per thread
#define NSPLIT 2   // atom-range split: grid 2048 -> 8 blocks/CU

// readlane: value from lane `l` -> SGPR-resident (uniform) float
__device__ inline float rlane(float v, int l) {
    return __int_as_float(__builtin_amdgcn_readlane(__float_as_int(v), l));
}

__launch_bounds__(BLOCK, 8)
__global__ void fape_fused(const float* __restrict__ pred,
                           const float* __restrict__ tru,
                           float* __restrict__ out, int N, int F, float inv) {
    const int lane = threadIdx.x & 63;
    const int g = blockIdx.x >> 1;            // frame group (NSPLIT==2)
    const int s = blockIdx.x & (NSPLIT - 1);  // atom slice
    const int f0 = g * FPB;

    // ---- lean prologue: each lane builds ONE frame (<=~30 live VGPRs) ----
    // lane l: frame f0+(l&3), src = pred if (l&4)==0 else true. Lanes 8..63
    // compute redundantly; only lanes 0..7 are consumed via shfl/readlane.
    int fi = f0 + (lane & 3);
    if (fi >= F) fi = F - 1;   // pad frames masked by w=0 below
    const float* src = ((lane & 4) == 0) ? pred : tru;
    float O[12];
    {
        const float* p = src + 3 * fi;
        float c0x = p[0], c0y = p[1], c0z = p[2];
        float c1x = p[3], c1y = p[4], c1z = p[5];
        float c2x = p[6], c2y = p[7], c2z = p[8];
        // e1 = normalize(c2-c1); e2 = normalize(GS(c0-c1, e1)); e3 = e1 x e2
        float e1x = c2x - c1x, e1y = c2y - c1y, e1z = c2z - c1z;
        float n1 = __builtin_amdgcn_sqrtf(e1x*e1x + e1y*e1y + e1z*e1z) + EPSF;
        float r1 = __builtin_amdgcn_rcpf(n1);
        e1x *= r1; e1y *= r1; e1z *= r1;
        float ax = c0x - c1x, ay = c0y - c1y, az = c0z - c1z;
        float d = ax*e1x + ay*e1y + az*e1z;
        ax -= d*e1x; ay -= d*e1y; az -= d*e1z;
        float n2 = __builtin_amdgcn_sqrtf(ax*ax + ay*ay + az*az) + EPSF;
        float r2 = __builtin_amdgcn_rcpf(n2);
        ax *= r2; ay *= r2; az *= r2;
        float bx = e1y*az - e1z*ay;
        float by = e1z*ax - e1x*az;
        float bz = e1x*ay - e1y*ax;
        O[0] = c1x; O[1]  = c1y; O[2]  = c1z;
        O[3] = e1x; O[4]  = e1y; O[5]  = e1z;
        O[6] = ax;  O[7]  = ay;  O[8]  = az;
        O[9] = bx;  O[10] = by;  O[11] = bz;
    }

    // every lane gathers (P,T) of frame (lane&3) and computes the fused
    // transform Dv: Dv[0..2] = v = o_p - M*o_t, Dv[3..11] = M = Rp^T*Rt,
    // so that |Rp(p-o_p) - Rt(t-o_t)| == |(p - v) - M*t|.
    float P[12], T[12];
#pragma unroll
    for (int j = 0; j < 12; j++) {
        P[j] = __shfl(O[j], (lane & 3), 64);
        T[j] = __shfl(O[j], (lane & 3) + 4, 64);
    }
    float Dv[12];
#pragma unroll
    for (int i = 0; i < 3; i++)
#pragma unroll
        for (int j = 0; j < 3; j++)
            Dv[3 + 3*i + j] = P[3+i]*T[3+j] + P[6+i]*T[6+j] + P[9+i]*T[9+j];
    Dv[0] = P[0] - (Dv[3]*T[0] + Dv[4] *T[1] + Dv[5] *T[2]);
    Dv[1] = P[1] - (Dv[6]*T[0] + Dv[7] *T[1] + Dv[8] *T[2]);
    Dv[2] = P[2] - (Dv[9]*T[0] + Dv[10]*T[1] + Dv[11]*T[2]);

    // frame constants -> SGPRs (lane i holds frame i's Dv, i = 0..3)
    float C[FPB][12];
#pragma unroll
    for (int i = 0; i < FPB; i++)
#pragma unroll
        for (int j = 0; j < 12; j++)
            C[i][j] = rlane(Dv[j], i);

    float w[FPB], acc[FPB];
#pragma unroll
    for (int i = 0; i < FPB; i++) {
        w[i] = (f0 + i < F) ? 1.0f : 0.0f;   // uniform -> scalar
        acc[i] = 0.0f;
    }

    // ---- main (frame x atom) loop: ~45 VGPRs, SGPR frame constants ----
    const int span = N / NSPLIT;        // 2048 = 2 chunks of BLOCK*AT=1024
    const int base = s * span;
    float px[AT], py[AT], pz[AT], tx[AT], ty[AT], tz[AT];
    for (int c = 0; c < span; c += BLOCK * AT) {
#pragma unroll
        for (int a = 0; a < AT; a++) {
            int n = base + c + threadIdx.x + a * BLOCK;
            const float* pp = pred + 3 * n;
            px[a] = pp[0]; py[a] = pp[1]; pz[a] = pp[2];
            const float* tp = tru + 3 * n;
            tx[a] = tp[0]; ty[a] = tp[1]; tz[a] = tp[2];
        }
#pragma unroll
        for (int i = 0; i < FPB; i++) {
#pragma unroll
            for (int a = 0; a < AT; a++) {
                // c = (p - v) - M*t : 18 VALU ops/pair (1 SGPR operand each)
                float cx = fmaf(-C[i][3], tx[a], fmaf(-C[i][4], ty[a],
                             fmaf(-C[i][5], tz[a], px[a] - C[i][0])));
                float cy = fmaf(-C[i][6], tx[a], fmaf(-C[i][7], ty[a],
                             fmaf(-C[i][8], tz[a], py[a] - C[i][1])));
                float cz = fmaf(-C[i][9], tx[a], fmaf(-C[i][10], ty[a],
                             fmaf(-C[i][11], tz[a], pz[a] - C[i][2])));
                float d2 = fmaf(cz, cz, fmaf(cy, cy, fmaf(cx, cx, EPSF)));
                float dist = __builtin_amdgcn_sqrtf(d2);
                acc[i] += fminf(dist, 10.0f);
            }
        }
    }

    float t = 0.0f;
#pragma unroll
    for (int i = 0; i < FPB; i++) t = fmaf(w[i], acc[i], t);

    // wave (64) shuffle reduction, cross-wave via LDS, one atomic per block
#pragma unroll
    for (int off = 32; off > 0; off >>= 1) t += __shfl_down(t, off, 64);
    __shared__ float sred[BLOCK / 64];
    if (lane == 0) sred[threadIdx.x >> 6] = t;
    __syncthreads();
    if (threadIdx.x == 0) {
        float z = 0.0f;
#pragma unroll
        for (int i = 0; i < BLOCK / 64; i++) z += sred[i];
        atomicAdd(out, z * inv);
    }
}

extern "C" void kernel_launch(void* const* d_in, const int* in_sizes, int n_in,
                              void* d_out, int out_size, void* d_ws, size_t ws_size,
                              hipStream_t stream) {
    const float* pred = (const float*)d_in[0];
    const float* tru  = (const float*)d_in[1];
    float* out = (float*)d_out;

    int N = in_sizes[0] / 3;            // 4096
    int F = N - 2;                      // 4094
    int groups = (F + FPB - 1) / FPB;   // 1024
    int grid = groups * NSPLIT;         // 2048

    hipMemsetAsync(out, 0, sizeof(float), stream);  // d_out poisoned 0xAA

    float inv = 1.0f / ((float)F * (float)N * 10.0f);
    fape_fused<<<grid, BLOCK, 0, stream>>>(pred, tru, out, N, F, inv);
}

// Round 6
// 68.596 us; speedup vs baseline: 1.2690x; 1.2690x over previous
//
#include <hip/hip_runtime.h>

#define EPSF 1e-8f
#define FPB 4      // frames per group
#define BLOCK 256
#define AT 4       // atoms per thread per chunk
#define NSPLIT 2   // grid = 1024*2 = 2048 blocks = 8 blocks/CU (full residency)

// readfirstlane: uniform value -> SGPR-resident float
__device__ inline float rf(float v) {
    return __int_as_float(__builtin_amdgcn_readfirstlane(__float_as_int(v)));
}

// ---------- Kernel A: per-frame fused transform (VGPR-unconstrained) -------
// fr[f][0..2] = v = o_p - M*o_t ; fr[f][3..11] = M = Rp^T*Rt (row-major).
// |Rp(p-o_p) - Rt(t-o_t)| == |(p - v) - M*t| since Rp is orthonormal.
__device__ inline void compute_frame(const float* __restrict__ c, int f,
                                     float* __restrict__ o) {
    const float* p = c + 3 * f;
    float c0x = p[0], c0y = p[1], c0z = p[2];
    float c1x = p[3], c1y = p[4], c1z = p[5];
    float c2x = p[6], c2y = p[7], c2z = p[8];
    float e1x = c2x - c1x, e1y = c2y - c1y, e1z = c2z - c1z;
    float n1 = __builtin_amdgcn_sqrtf(e1x*e1x + e1y*e1y + e1z*e1z) + EPSF;
    float r1 = __builtin_amdgcn_rcpf(n1);
    e1x *= r1; e1y *= r1; e1z *= r1;
    float ax = c0x - c1x, ay = c0y - c1y, az = c0z - c1z;
    float d = ax*e1x + ay*e1y + az*e1z;
    ax -= d*e1x; ay -= d*e1y; az -= d*e1z;
    float n2 = __builtin_amdgcn_sqrtf(ax*ax + ay*ay + az*az) + EPSF;
    float r2 = __builtin_amdgcn_rcpf(n2);
    ax *= r2; ay *= r2; az *= r2;
    float bx = e1y*az - e1z*ay;
    float by = e1z*ax - e1x*az;
    float bz = e1x*ay - e1y*ax;
    o[0] = c1x; o[1]  = c1y; o[2]  = c1z;
    o[3] = e1x; o[4]  = e1y; o[5]  = e1z;
    o[6] = ax;  o[7]  = ay;  o[8]  = az;
    o[9] = bx;  o[10] = by;  o[11] = bz;
}

__global__ void frames_kernel(const float* __restrict__ pred,
                              const float* __restrict__ tru,
                              float* __restrict__ fr, int F, int Fpad) {
    int f = blockIdx.x * blockDim.x + threadIdx.x;
    if (f >= Fpad) return;
    float* D = fr + 12 * f;
    if (f < F) {
        float P[12], T[12], M[9];
        compute_frame(pred, f, P);
        compute_frame(tru,  f, T);
#pragma unroll
        for (int i = 0; i < 3; i++)
#pragma unroll
            for (int j = 0; j < 3; j++)
                M[3*i+j] = P[3+i]*T[3+j] + P[6+i]*T[6+j] + P[9+i]*T[9+j];
        D[0] = P[0] - (M[0]*T[0] + M[1]*T[1] + M[2]*T[2]);
        D[1] = P[1] - (M[3]*T[0] + M[4]*T[1] + M[5]*T[2]);
        D[2] = P[2] - (M[6]*T[0] + M[7]*T[1] + M[8]*T[2]);
#pragma unroll
        for (int j = 0; j < 9; j++) D[3+j] = M[j];
    } else {
        // finite identity pad; masked by w=0 in fape_main
        D[0]=0.f; D[1]=0.f; D[2]=0.f;
        D[3]=1.f; D[4]=0.f; D[5]=0.f;
        D[6]=0.f; D[7]=1.f; D[8]=0.f;
        D[9]=0.f; D[10]=0.f; D[11]=1.f;
    }
}

// ---------- Kernel B: hot loop, ~50 live VGPRs, constants in SGPRs ---------
__launch_bounds__(BLOCK, 8)
__global__ void fape_main(const float* __restrict__ pred,
                          const float* __restrict__ tru,
                          const float* __restrict__ fr,
                          float* __restrict__ part, int N, int F) {
    const int g = blockIdx.x >> 1;            // frame group (NSPLIT==2)
    const int s = blockIdx.x & (NSPLIT - 1);  // atom slice
    const int f0 = g * FPB;

    // 48 uniform frame constants -> SGPRs via readfirstlane (12 float4 loads)
    float C[FPB][12];
#pragma unroll
    for (int i = 0; i < FPB; i++) {
        const float4* q = (const float4*)(fr + 12 * (f0 + i));  // 16B-aligned
        float4 qa = q[0], qb = q[1], qc = q[2];
        C[i][0] = rf(qa.x); C[i][1]  = rf(qa.y); C[i][2]  = rf(qa.z);
        C[i][3] = rf(qa.w); C[i][4]  = rf(qb.x); C[i][5]  = rf(qb.y);
        C[i][6] = rf(qb.z); C[i][7]  = rf(qb.w); C[i][8]  = rf(qc.x);
        C[i][9] = rf(qc.y); C[i][10] = rf(qc.z); C[i][11] = rf(qc.w);
    }

    float w[FPB], acc[FPB];
#pragma unroll
    for (int i = 0; i < FPB; i++) {
        w[i] = (f0 + i < F) ? 1.0f : 0.0f;   // uniform
        acc[i] = 0.0f;
    }

    const int span = N / NSPLIT;             // 2048 = 2 chunks of 1024
    const int base = s * span;
    float px[AT], py[AT], pz[AT], tx[AT], ty[AT], tz[AT];
    for (int c = 0; c < span; c += BLOCK * AT) {
#pragma unroll
        for (int a = 0; a < AT; a++) {
            int n = base + c + threadIdx.x + a * BLOCK;
            const float* pp = pred + 3 * n;
            px[a] = pp[0]; py[a] = pp[1]; pz[a] = pp[2];
            const float* tp = tru + 3 * n;
            tx[a] = tp[0]; ty[a] = tp[1]; tz[a] = tp[2];
        }
#pragma unroll
        for (int i = 0; i < FPB; i++) {
#pragma unroll
            for (int a = 0; a < AT; a++) {
                // c = (p - v) - M*t : 18 VALU ops/pair, 1 SGPR operand each
                float cx = fmaf(-C[i][3], tx[a], fmaf(-C[i][4], ty[a],
                             fmaf(-C[i][5], tz[a], px[a] - C[i][0])));
                float cy = fmaf(-C[i][6], tx[a], fmaf(-C[i][7], ty[a],
                             fmaf(-C[i][8], tz[a], py[a] - C[i][1])));
                float cz = fmaf(-C[i][9], tx[a], fmaf(-C[i][10], ty[a],
                             fmaf(-C[i][11], tz[a], pz[a] - C[i][2])));
                float d2 = fmaf(cz, cz, fmaf(cy, cy, fmaf(cx, cx, EPSF)));
                float dist = __builtin_amdgcn_sqrtf(d2);
                acc[i] += fminf(dist, 10.0f);
            }
        }
    }

    float t = 0.0f;
#pragma unroll
    for (int i = 0; i < FPB; i++) t = fmaf(w[i], acc[i], t);

    // wave reduce (64) -> cross-wave via LDS -> one plain store per block
#pragma unroll
    for (int off = 32; off > 0; off >>= 1) t += __shfl_down(t, off, 64);
    __shared__ float sred[BLOCK / 64];
    const int lane = threadIdx.x & 63;
    if (lane == 0) sred[threadIdx.x >> 6] = t;
    __syncthreads();
    if (threadIdx.x == 0) {
        float z = 0.0f;
#pragma unroll
        for (int i = 0; i < BLOCK / 64; i++) z += sred[i];
        part[blockIdx.x] = z;           // no atomics: deterministic partials
    }
}

// ---------- Kernel C: reduce 2048 partials, write the scalar ---------------
__global__ void reduce_kernel(const float* __restrict__ part,
                              float* __restrict__ out, int nb, float inv) {
    float s = 0.0f;
    for (int i = threadIdx.x; i < nb; i += BLOCK) s += part[i];
#pragma unroll
    for (int off = 32; off > 0; off >>= 1) s += __shfl_down(s, off, 64);
    __shared__ float sred[BLOCK / 64];
    const int lane = threadIdx.x & 63;
    if (lane == 0) sred[threadIdx.x >> 6] = s;
    __syncthreads();
    if (threadIdx.x == 0) {
        float z = 0.0f;
#pragma unroll
        for (int i = 0; i < BLOCK / 64; i++) z += sred[i];
        out[0] = z * inv;               // overwrites poison; no memset needed
    }
}

extern "C" void kernel_launch(void* const* d_in, const int* in_sizes, int n_in,
                              void* d_out, int out_size, void* d_ws, size_t ws_size,
                              hipStream_t stream) {
    const float* pred = (const float*)d_in[0];
    const float* tru  = (const float*)d_in[1];
    float* out = (float*)d_out;

    int N = in_sizes[0] / 3;            // 4096
    int F = N - 2;                      // 4094
    int groups = (F + FPB - 1) / FPB;   // 1024
    int Fpad = groups * FPB;            // 4096
    int gridB = groups * NSPLIT;        // 2048

    float* fr   = (float*)d_ws;                 // Fpad*12 floats (~197 KB)
    float* part = fr + (size_t)Fpad * 12;       // gridB floats

    int gridA = (Fpad + BLOCK - 1) / BLOCK;     // 16
    frames_kernel<<<gridA, BLOCK, 0, stream>>>(pred, tru, fr, F, Fpad);

    fape_main<<<gridB, BLOCK, 0, stream>>>(pred, tru, fr, part, N, F);

    float inv = 1.0f / ((float)F * (float)N * 10.0f);
    reduce_kernel<<<1, BLOCK, 0, stream>>>(part, out, gridB, inv);
}